// Round 4
// baseline (180.853 us; speedup 1.0000x reference)
//
#include <hip/hip_runtime.h>

// VQ-VAE codebook lookup: z_e [32,2048,64] f32, codebook [1024,64] f32.
// Out = concat(z_q [65536*64] f32, indices [65536] written as f32).
// dist(n,k) = ||x||^2 - 2 x.c + ||c||^2, argmin, first-occurrence tie-break.
//
// 128 rows x 1024 codes per block (8 chunks of 128 codes). xT/cT transposed
// in LDS, skewed (stride 140, col = c + 4*(c>>5)) -> <=2-way conflicts (free).
// 8x8 register micro-tile. Round-3 additions:
//   * 2-deep software-pipelined d-loop (hide ~120cy LDS latency in-wave)
//   * T14 staging split: next cT chunk's global loads issued before compute,
//     LDS writes after the post-compute barrier (hide L2 latency)
//   * one padding row on xT/cT so the d+2 prefetch at d=62 is branch-free

#define N_ROWS  65536
#define D       64
#define K_CODES 1024
#define M_TILE  128
#define N_CHUNK 128
#define N_CHUNKS (K_CODES / N_CHUNK)
#define STRIDE  140
#define COL(x)  ((x) + 4 * ((x) >> 5))

__global__ __launch_bounds__(256) void c2_kernel(const float* __restrict__ cb,
                                                 float* __restrict__ c2) {
    int c = blockIdx.x * 256 + threadIdx.x;
    if (c >= K_CODES) return;
    const float4* row = (const float4*)(cb + c * D);
    float s0 = 0.f, s1 = 0.f, s2 = 0.f, s3 = 0.f;
#pragma unroll
    for (int i = 0; i < D / 4; ++i) {
        float4 v = row[i];
        s0 = fmaf(v.x, v.x, s0);
        s1 = fmaf(v.y, v.y, s1);
        s2 = fmaf(v.z, v.z, s2);
        s3 = fmaf(v.w, v.w, s3);
    }
    c2[c] = (s0 + s1) + (s2 + s3);
}

__global__ __launch_bounds__(256, 2) void vq_kernel(const float* __restrict__ z_e,
                                                    const float* __restrict__ cb,
                                                    const float* __restrict__ c2g,
                                                    float* __restrict__ out) {
    __shared__ float xT[65 * STRIDE];   // [d][row], +1 pad row for prefetch
    __shared__ float cT[65 * STRIDE];   // [d][code], +1 pad row
    __shared__ float x2_l[M_TILE];

    const int tid      = threadIdx.x;
    const int row_base = blockIdx.x * M_TILE;
    const int ti = tid >> 4;    // row group (8 rows)
    const int tj = tid & 15;    // code group (8 codes)
    const int sseg = tid >> 4;  // staging: dim segment 4*sseg..4*sseg+3
    const int srow = tid & 15;  // staging: row/code mod 16

    // ---- prologue: stage xT and cT(chunk 0); all 16 loads in flight ----
    float4 xs[8], cs[8];
#pragma unroll
    for (int ii = 0; ii < 8; ++ii)
        xs[ii] = *(const float4*)(z_e + (size_t)(row_base + srow + 16 * ii) * D + 4 * sseg);
#pragma unroll
    for (int ii = 0; ii < 8; ++ii)
        cs[ii] = *(const float4*)(cb + (size_t)(srow + 16 * ii) * D + 4 * sseg);
#pragma unroll
    for (int ii = 0; ii < 8; ++ii) {
        const int col = COL(srow + 16 * ii);
        xT[(4 * sseg + 0) * STRIDE + col] = xs[ii].x;
        xT[(4 * sseg + 1) * STRIDE + col] = xs[ii].y;
        xT[(4 * sseg + 2) * STRIDE + col] = xs[ii].z;
        xT[(4 * sseg + 3) * STRIDE + col] = xs[ii].w;
        cT[(4 * sseg + 0) * STRIDE + col] = cs[ii].x;
        cT[(4 * sseg + 1) * STRIDE + col] = cs[ii].y;
        cT[(4 * sseg + 2) * STRIDE + col] = cs[ii].z;
        cT[(4 * sseg + 3) * STRIDE + col] = cs[ii].w;
    }
    __syncthreads();

    // ---- x2 for the 128 rows ----
    if (tid < M_TILE) {
        const int col = COL(tid);
        float a = 0.f, b = 0.f, c = 0.f, e = 0.f;
#pragma unroll
        for (int d = 0; d < 64; d += 4) {
            float v0 = xT[(d + 0) * STRIDE + col];
            float v1 = xT[(d + 1) * STRIDE + col];
            float v2 = xT[(d + 2) * STRIDE + col];
            float v3 = xT[(d + 3) * STRIDE + col];
            a = fmaf(v0, v0, a);
            b = fmaf(v1, v1, b);
            c = fmaf(v2, v2, c);
            e = fmaf(v3, v3, e);
        }
        x2_l[tid] = (a + b) + (c + e);
    }
    __syncthreads();

    float x2r[8];
#pragma unroll
    for (int r = 0; r < 8; ++r) x2r[r] = x2_l[8 * ti + r];

    float best[8];
    int   bidx[8];
#pragma unroll
    for (int r = 0; r < 8; ++r) { best[r] = 3.4e38f; bidx[r] = 0; }

    const int cxa = COL(8 * ti), cxb = cxa + 4;
    const int cca = COL(8 * tj), ccb = cca + 4;

#define LDX(dd, off) (*(const float4*)&xT[(dd) * STRIDE + (off)])
#define LDC(dd, off) (*(const float4*)&cT[(dd) * STRIDE + (off)])
#define FMA8x8(S)                                                              \
    do {                                                                       \
        const float xv[8] = {xa##S.x, xa##S.y, xa##S.z, xa##S.w,               \
                             xb##S.x, xb##S.y, xb##S.z, xb##S.w};              \
        const float cv[8] = {ca##S.x, ca##S.y, ca##S.z, ca##S.w,               \
                             cb##S.x, cb##S.y, cb##S.z, cb##S.w};              \
        _Pragma("unroll") for (int r = 0; r < 8; ++r)                          \
            _Pragma("unroll") for (int q = 0; q < 8; ++q)                      \
                acc[r][q] = fmaf(xv[r], cv[q], acc[r][q]);                     \
    } while (0)

    for (int ch = 0; ch < N_CHUNKS; ++ch) {
        // T14: issue next chunk's codebook loads now; write after compute.
        if (ch + 1 < N_CHUNKS) {
#pragma unroll
            for (int ii = 0; ii < 8; ++ii)
                cs[ii] = *(const float4*)(cb +
                    (size_t)((ch + 1) * N_CHUNK + srow + 16 * ii) * D + 4 * sseg);
        }
        // c2 for this thread's 8 codes (hoisted above d-loop; latency hidden)
        const float4 c20 = *(const float4*)(c2g + ch * N_CHUNK + 8 * tj);
        const float4 c21 = *(const float4*)(c2g + ch * N_CHUNK + 8 * tj + 4);

        float acc[8][8];
#pragma unroll
        for (int r = 0; r < 8; ++r)
#pragma unroll
            for (int q = 0; q < 8; ++q) acc[r][q] = 0.f;

        // ---- 2-deep software-pipelined depth loop ----
        float4 xaA, xbA, caA, cbA, xaB, xbB, caB, cbB;
        xaA = LDX(0, cxa); xbA = LDX(0, cxb);
        caA = LDC(0, cca); cbA = LDC(0, ccb);
#pragma unroll 8
        for (int d = 0; d < 64; d += 2) {
            xaB = LDX(d + 1, cxa); xbB = LDX(d + 1, cxb);
            caB = LDC(d + 1, cca); cbB = LDC(d + 1, ccb);
            FMA8x8(A);
            // d=62 prefetches row 64 -> lands in the pad row, values unused
            xaA = LDX(d + 2, cxa); xbA = LDX(d + 2, cxb);
            caA = LDC(d + 2, cca); cbA = LDC(d + 2, ccb);
            FMA8x8(B);
        }

        // ---- fused distance + running argmin ----
        const float c2v[8] = {c20.x, c20.y, c20.z, c20.w,
                              c21.x, c21.y, c21.z, c21.w};
#pragma unroll
        for (int q = 0; q < 8; ++q) {
            const int code = ch * N_CHUNK + 8 * tj + q;
#pragma unroll
            for (int r = 0; r < 8; ++r) {
                const float dist = fmaf(-2.f, acc[r][q], x2r[r] + c2v[q]);
                if (dist < best[r]) { best[r] = dist; bidx[r] = code; }
            }
        }

        if (ch + 1 < N_CHUNKS) {
            __syncthreads();   // all reads of cT done
#pragma unroll
            for (int ii = 0; ii < 8; ++ii) {
                const int col = COL(srow + 16 * ii);
                cT[(4 * sseg + 0) * STRIDE + col] = cs[ii].x;
                cT[(4 * sseg + 1) * STRIDE + col] = cs[ii].y;
                cT[(4 * sseg + 2) * STRIDE + col] = cs[ii].z;
                cT[(4 * sseg + 3) * STRIDE + col] = cs[ii].w;
            }
            __syncthreads();   // cT(ch+1) visible
        }
    }

    // ---- reduce (best, idx) across the 16 lanes of this row group ----
#pragma unroll
    for (int off = 1; off < 16; off <<= 1) {
#pragma unroll
        for (int r = 0; r < 8; ++r) {
            const float ob = __shfl_xor(best[r], off);
            const int   oi = __shfl_xor(bidx[r], off);
            if (ob < best[r] || (ob == best[r] && oi < bidx[r])) {
                best[r] = ob; bidx[r] = oi;
            }
        }
    }

    // ---- write z_q (coalesced float4) and indices ----
#pragma unroll
    for (int r = 0; r < 8; ++r) {
        const int row = row_base + 8 * ti + r;
        const float4 v = *(const float4*)(cb + (size_t)bidx[r] * D + 4 * tj);
        *(float4*)(out + (size_t)row * D + 4 * tj) = v;
    }
    if (tj < 8) out[(size_t)N_ROWS * D + row_base + 8 * ti + tj] = (float)bidx[tj];
}

extern "C" void kernel_launch(void* const* d_in, const int* in_sizes, int n_in,
                              void* d_out, int out_size, void* d_ws, size_t ws_size,
                              hipStream_t stream) {
    const float* z_e = (const float*)d_in[0];
    const float* cb  = (const float*)d_in[1];
    float* out = (float*)d_out;
    float* c2  = (float*)d_ws;  // 1024 floats scratch

    hipLaunchKernelGGL(c2_kernel, dim3(K_CODES / 256), dim3(256), 0, stream, cb, c2);
    hipLaunchKernelGGL(vq_kernel, dim3(N_ROWS / M_TILE), dim3(256), 0, stream,
                       z_e, cb, c2, out);
}